// Round 2
// baseline (5472.298 us; speedup 1.0000x reference)
//
#include <hip/hip_runtime.h>
#include <math.h>

#define NBATCH 512
#define NPTS   128
#define KNN    20
#define NFEAT  16
#define INVN   (1.0 / 1310720.0)   // 1 / (B*N*K)

typedef unsigned char uchar;

// ---- block stats: each thread holds SPAN channels at wave-uniform offset co ----
// butterfly over the 64-lane wave sums all point/k-split partials automatically.
template<int C, int SPAN>
__device__ inline void block_stats_span(const float* ls, const float* lq, int co,
                                        double* __restrict__ gsum, double* __restrict__ gsq){
  __shared__ float ssum[C];
  __shared__ float ssq[C];
  const int t = threadIdx.x;
  if (t < C){ ssum[t] = 0.f; ssq[t] = 0.f; }
  __syncthreads();
  #pragma unroll
  for (int c = 0; c < SPAN; ++c){
    float a = ls[c], q = lq[c];
    #pragma unroll
    for (int m = 32; m; m >>= 1){ a += __shfl_xor(a, m, 64); q += __shfl_xor(q, m, 64); }
    if ((t & 63) == 0){ atomicAdd(&ssum[co + c], a); atomicAdd(&ssq[co + c], q); }
  }
  __syncthreads();
  if (t < C){
    unsafeAtomicAdd(&gsum[t], (double)ssum[t]);
    unsafeAtomicAdd(&gsq[t],  (double)ssq[t]);
  }
}

// ---------------- KNN on 2-D points: 4-way j-split + LDS merge ----------------
__global__ __launch_bounds__(256) void knn1_kernel(const float* __restrict__ pts,
                                                   uchar* __restrict__ idx_out){
  const int b = blockIdx.x >> 1, half = blockIdx.x & 1;
  const int t = threadIdx.x;
  const int js = t >> 6;        // wave id = candidate split
  const int nl = t & 63;        // local point
  const int n  = half * 64 + nl;
  __shared__ float px[128], py[128], sq[128];
  __shared__ float ld[64][4][20];
  __shared__ uchar li[64][4][20];
  const float* p = pts + (size_t)b * 128 * 2;
  { float v = p[t]; if ((t & 1) == 0) px[t >> 1] = v; else py[t >> 1] = v; }
  __syncthreads();
  if (t < 128) sq[t] = px[t]*px[t] + py[t]*py[t];
  __syncthreads();
  const float x = px[n], y = py[n], sqn = sq[n];
  float bd[KNN]; int bi[KNN];
  #pragma unroll
  for (int q = 0; q < KNN; ++q){ bd[q] = 3.0e38f; bi[q] = 0; }
  const int j0 = js * 32;
  for (int jj = 0; jj < 32; ++jj){
    const int j = j0 + jj;
    float d = sqn + sq[j] - 2.0f*(x*px[j] + y*py[j]);
    if (j == n) d += 1.0e9f;
    float cd = d; int ci = j;
    #pragma unroll
    for (int q = 0; q < KNN; ++q){
      if (cd < bd[q]){ float td=bd[q]; bd[q]=cd; cd=td; int ti=bi[q]; bi[q]=ci; ci=ti; }
    }
  }
  #pragma unroll
  for (int q = 0; q < KNN; ++q){ ld[nl][js][q] = bd[q]; li[nl][js][q] = (uchar)bi[q]; }
  __syncthreads();
  if (js == 0){  // wave 0 merges 4 sorted lists per point (strict < => lower j wins ties)
    int p0=0,p1=0,p2=0,p3=0;
    float v0=ld[nl][0][0], v1=ld[nl][1][0], v2=ld[nl][2][0], v3=ld[nl][3][0];
    uchar* o = idx_out + ((size_t)b*128 + n) * KNN;
    #pragma unroll
    for (int q = 0; q < KNN; ++q){
      int sel = 0; float vm = v0;
      if (v1 < vm){ vm = v1; sel = 1; }
      if (v2 < vm){ vm = v2; sel = 2; }
      if (v3 < vm){ vm = v3; sel = 3; }
      const int psel = (sel==0)?p0:(sel==1)?p1:(sel==2)?p2:p3;
      o[q] = li[nl][sel][psel];
      const int pn = psel + 1;
      const float nv = (pn < KNN) ? ld[nl][sel][pn] : 3.4e38f;
      p0 += (sel==0); v0 = (sel==0)? nv : v0;
      p1 += (sel==1); v1 = (sel==1)? nv : v1;
      p2 += (sel==2); v2 = (sel==2)? nv : v2;
      p3 += (sel==3); v3 = (sel==3)? nv : v3;
    }
  }
}

// ---------------- KNN on 32-D features: 4-way j-split + LDS merge ----------------
__global__ __launch_bounds__(256) void knn2_kernel(const float* __restrict__ x1,
                                                   uchar* __restrict__ idx_out){
  const int b = blockIdx.x >> 1, half = blockIdx.x & 1;
  const int t = threadIdx.x;
  const int js = t >> 6, nl = t & 63, n = half*64 + nl;
  __shared__ float xs[128][33];
  __shared__ float sq[128];
  __shared__ float ld[64][4][20];
  __shared__ uchar li[64][4][20];
  const float* xb = x1 + (size_t)b * 128 * 32;
  for (int i = t; i < 4096; i += 256) xs[i >> 5][i & 31] = xb[i];
  __syncthreads();
  if (t < 128){
    float s = 0.f;
    #pragma unroll
    for (int c = 0; c < 32; ++c){ float v = xs[t][c]; s += v*v; }
    sq[t] = s;
  }
  __syncthreads();
  float xt[32];
  #pragma unroll
  for (int c = 0; c < 32; ++c) xt[c] = xs[n][c];
  const float sqn = sq[n];
  float bd[KNN]; int bi[KNN];
  #pragma unroll
  for (int q = 0; q < KNN; ++q){ bd[q] = 3.0e38f; bi[q] = 0; }
  const int j0 = js * 32;
  for (int jj = 0; jj < 32; ++jj){
    const int j = j0 + jj;
    float dot = 0.f;
    #pragma unroll
    for (int c = 0; c < 32; ++c) dot = fmaf(xt[c], xs[j][c], dot);
    float d = sqn + sq[j] - 2.0f*dot;
    if (j == n) d += 1.0e9f;
    float cd = d; int ci = j;
    #pragma unroll
    for (int q = 0; q < KNN; ++q){
      if (cd < bd[q]){ float td=bd[q]; bd[q]=cd; cd=td; int ti=bi[q]; bi[q]=ci; ci=ti; }
    }
  }
  #pragma unroll
  for (int q = 0; q < KNN; ++q){ ld[nl][js][q] = bd[q]; li[nl][js][q] = (uchar)bi[q]; }
  __syncthreads();
  if (js == 0){
    int p0=0,p1=0,p2=0,p3=0;
    float v0=ld[nl][0][0], v1=ld[nl][1][0], v2=ld[nl][2][0], v3=ld[nl][3][0];
    uchar* o = idx_out + ((size_t)b*128 + n) * KNN;
    #pragma unroll
    for (int q = 0; q < KNN; ++q){
      int sel = 0; float vm = v0;
      if (v1 < vm){ vm = v1; sel = 1; }
      if (v2 < vm){ vm = v2; sel = 2; }
      if (v3 < vm){ vm = v3; sel = 3; }
      const int psel = (sel==0)?p0:(sel==1)?p1:(sel==2)?p2:p3;
      o[q] = li[nl][sel][psel];
      const int pn = psel + 1;
      const float nv = (pn < KNN) ? ld[nl][sel][pn] : 3.4e38f;
      p0 += (sel==0); v0 = (sel==0)? nv : v0;
      p1 += (sel==1); v1 = (sel==1)? nv : v1;
      p2 += (sel==2); v2 = (sel==2)? nv : v2;
      p3 += (sel==3); v3 = (sel==3)? nv : v3;
    }
  }
}

// ---------------- EC1 pass1: stats of h1 (k-split x4) ----------------
__global__ __launch_bounds__(256) void ec1_pass1(
    const float* __restrict__ feat, const uchar* __restrict__ idx,
    const float* __restrict__ W1, const float* __restrict__ B1,
    double* __restrict__ stat){
  const int t = threadIdx.x;
  const int sub = t & 3;
  const int p = blockIdx.x*64 + (t >> 2);
  const int b = p >> 7, n = p & 127;
  const float* Xb = feat + (size_t)b * 128 * NFEAT;
  float xi[NFEAT];
  #pragma unroll
  for (int i = 0; i < NFEAT; ++i) xi[i] = Xb[n*NFEAT + i];
  float hb[32];
  #pragma unroll
  for (int c = 0; c < 32; ++c) hb[c] = B1[c];
  #pragma unroll
  for (int i = 0; i < NFEAT; ++i){
    const float v = xi[i];
    #pragma unroll
    for (int c = 0; c < 32; ++c) hb[c] = fmaf(v, W1[i*32 + c], hb[c]);
  }
  const uchar* id = idx + (size_t)p * KNN;
  float ls[32], lq[32];
  #pragma unroll
  for (int c = 0; c < 32; ++c){ ls[c] = 0.f; lq[c] = 0.f; }
  for (int kk = 0; kk < 5; ++kk){
    const int j = id[sub + kk*4];
    float h[32];
    #pragma unroll
    for (int c = 0; c < 32; ++c) h[c] = hb[c];
    #pragma unroll
    for (int i = 0; i < NFEAT; ++i){
      const float d = Xb[j*NFEAT + i] - xi[i];
      #pragma unroll
      for (int c = 0; c < 32; ++c) h[c] = fmaf(d, W1[(NFEAT+i)*32 + c], h[c]);
    }
    #pragma unroll
    for (int c = 0; c < 32; ++c){ ls[c] += h[c]; lq[c] = fmaf(h[c], h[c], lq[c]); }
  }
  block_stats_span<32,32>(ls, lq, 0, stat, stat + 32);
}

// ---------------- EC1 pass2: recompute h1, BN+ReLU, h2 half, stats (kh2 x ch2) ----------------
__global__ __launch_bounds__(256) void ec1_pass2(
    const float* __restrict__ feat, const uchar* __restrict__ idx,
    const float* __restrict__ W1, const float* __restrict__ B1,
    const double* __restrict__ st1, const float* __restrict__ g1, const float* __restrict__ be1,
    const float* __restrict__ W2, const float* __restrict__ B2,
    double* __restrict__ stat){
  const int t = threadIdx.x;
  const int ch = t >> 7, kh = t & 1, pl = (t >> 1) & 63;
  const int p = blockIdx.x*64 + pl;
  const int b = p >> 7, n = p & 127;
  __shared__ float sc1l[32], sh1l[32];
  if (t < 32){
    const double m = st1[t]*INVN, v = st1[32+t]*INVN - m*m;
    const float s = (float)((double)g1[t] / sqrt(v + 1e-5));
    sc1l[t] = s; sh1l[t] = be1[t] - (float)m * s;
  }
  __syncthreads();
  const float* Xb = feat + (size_t)b * 128 * NFEAT;
  float xi[NFEAT];
  #pragma unroll
  for (int i = 0; i < NFEAT; ++i) xi[i] = Xb[n*NFEAT + i];
  float hb[32];
  #pragma unroll
  for (int c = 0; c < 32; ++c) hb[c] = B1[c];
  #pragma unroll
  for (int i = 0; i < NFEAT; ++i){
    const float v = xi[i];
    #pragma unroll
    for (int c = 0; c < 32; ++c) hb[c] = fmaf(v, W1[i*32 + c], hb[c]);
  }
  const uchar* id = idx + (size_t)p * KNN;
  const int co = ch * 16;
  float ls[16], lq[16];
  #pragma unroll
  for (int c = 0; c < 16; ++c){ ls[c] = 0.f; lq[c] = 0.f; }
  for (int kk = 0; kk < 10; ++kk){
    const int j = id[kh + kk*2];
    float h[32];
    #pragma unroll
    for (int c = 0; c < 32; ++c) h[c] = hb[c];
    #pragma unroll
    for (int i = 0; i < NFEAT; ++i){
      const float d = Xb[j*NFEAT + i] - xi[i];
      #pragma unroll
      for (int c = 0; c < 32; ++c) h[c] = fmaf(d, W1[(NFEAT+i)*32 + c], h[c]);
    }
    #pragma unroll
    for (int c = 0; c < 32; ++c) h[c] = fmaxf(fmaf(h[c], sc1l[c], sh1l[c]), 0.f);
    float h2[16];
    #pragma unroll
    for (int c = 0; c < 16; ++c) h2[c] = B2[co + c];
    #pragma unroll
    for (int i = 0; i < 32; ++i){
      const float v = h[i];
      #pragma unroll
      for (int c = 0; c < 16; ++c) h2[c] = fmaf(v, W2[i*32 + co + c], h2[c]);
    }
    #pragma unroll
    for (int c = 0; c < 16; ++c){ ls[c] += h2[c]; lq[c] = fmaf(h2[c], h2[c], lq[c]); }
  }
  block_stats_span<32,16>(ls, lq, co, stat, stat + 32);
}

// ---------------- EC1 pass3: mean_k(relu(bn(h2))) then @W3 (mean-commute) ----------------
__global__ __launch_bounds__(256) void ec1_pass3(
    const float* __restrict__ feat, const uchar* __restrict__ idx,
    const float* __restrict__ W1, const float* __restrict__ B1,
    const double* __restrict__ st1, const float* __restrict__ g1, const float* __restrict__ be1,
    const float* __restrict__ W2, const float* __restrict__ B2,
    const double* __restrict__ st2, const float* __restrict__ g2, const float* __restrict__ be2,
    const float* __restrict__ W3, const float* __restrict__ B3,
    float* __restrict__ x1){
  const int t = threadIdx.x;
  const int ch = t >> 7, kh = t & 1, pl = (t >> 1) & 63;
  const int p = blockIdx.x*64 + pl;
  const int b = p >> 7, n = p & 127;
  __shared__ float sc1l[32], sh1l[32], sc2l[32], sh2l[32];
  __shared__ float macc[64][33];
  if (t < 32){
    const double m = st1[t]*INVN, v = st1[32+t]*INVN - m*m;
    const float s = (float)((double)g1[t] / sqrt(v + 1e-5));
    sc1l[t] = s; sh1l[t] = be1[t] - (float)m * s;
  } else if (t < 64){
    const int c = t - 32;
    const double m = st2[c]*INVN, v = st2[32+c]*INVN - m*m;
    const float s = (float)((double)g2[c] / sqrt(v + 1e-5));
    sc2l[c] = s; sh2l[c] = be2[c] - (float)m * s;
  }
  __syncthreads();
  const float* Xb = feat + (size_t)b * 128 * NFEAT;
  float xi[NFEAT];
  #pragma unroll
  for (int i = 0; i < NFEAT; ++i) xi[i] = Xb[n*NFEAT + i];
  float hb[32];
  #pragma unroll
  for (int c = 0; c < 32; ++c) hb[c] = B1[c];
  #pragma unroll
  for (int i = 0; i < NFEAT; ++i){
    const float v = xi[i];
    #pragma unroll
    for (int c = 0; c < 32; ++c) hb[c] = fmaf(v, W1[i*32 + c], hb[c]);
  }
  const uchar* id = idx + (size_t)p * KNN;
  const int co = ch * 16;
  float acc[16];
  #pragma unroll
  for (int c = 0; c < 16; ++c) acc[c] = 0.f;
  for (int kk = 0; kk < 10; ++kk){
    const int j = id[kh + kk*2];
    float h[32];
    #pragma unroll
    for (int c = 0; c < 32; ++c) h[c] = hb[c];
    #pragma unroll
    for (int i = 0; i < NFEAT; ++i){
      const float d = Xb[j*NFEAT + i] - xi[i];
      #pragma unroll
      for (int c = 0; c < 32; ++c) h[c] = fmaf(d, W1[(NFEAT+i)*32 + c], h[c]);
    }
    #pragma unroll
    for (int c = 0; c < 32; ++c) h[c] = fmaxf(fmaf(h[c], sc1l[c], sh1l[c]), 0.f);
    float h2[16];
    #pragma unroll
    for (int c = 0; c < 16; ++c) h2[c] = B2[co + c];
    #pragma unroll
    for (int i = 0; i < 32; ++i){
      const float v = h[i];
      #pragma unroll
      for (int c = 0; c < 16; ++c) h2[c] = fmaf(v, W2[i*32 + co + c], h2[c]);
    }
    #pragma unroll
    for (int c = 0; c < 16; ++c) acc[c] += fmaxf(fmaf(h2[c], sc2l[co+c], sh2l[co+c]), 0.f);
  }
  #pragma unroll
  for (int c = 0; c < 16; ++c) acc[c] += __shfl_xor(acc[c], 1, 64);  // fold k-halves
  if (kh == 0){
    #pragma unroll
    for (int c = 0; c < 16; ++c) macc[pl][co + c] = acc[c] * (1.0f/KNN);
  }
  __syncthreads();
  // W3 phase: wave w -> output cols [w*8, w*8+8), lane = point
  const int w = t >> 6, nl2 = t & 63;
  const int pt = blockIdx.x*64 + nl2;
  float o8[8];
  #pragma unroll
  for (int c = 0; c < 8; ++c) o8[c] = B3[w*8 + c];
  #pragma unroll
  for (int i = 0; i < 32; ++i){
    const float v = macc[nl2][i];
    #pragma unroll
    for (int c = 0; c < 8; ++c) o8[c] = fmaf(v, W3[i*32 + w*8 + c], o8[c]);
  }
  float* o = x1 + (size_t)pt*32 + w*8;
  #pragma unroll
  for (int c = 0; c < 8; ++c) o[c] = o8[c];
}

// ---------------- EC2 pass1: stats of h4 (kh2 x cquarter4) ----------------
__global__ __launch_bounds__(256) void ec2_pass1(
    const float* __restrict__ x1, const uchar* __restrict__ idx,
    const float* __restrict__ W4, const float* __restrict__ B4,
    double* __restrict__ stat){
  const int t = threadIdx.x;
  const int cq = t >> 6, kh = t & 1, pl = (t >> 1) & 31;
  const int p = blockIdx.x*32 + pl;
  const int b = p >> 7, n = p & 127;
  const float* Xb = x1 + (size_t)b * 128 * 32;
  float xi[32];
  #pragma unroll
  for (int i = 0; i < 32; ++i) xi[i] = Xb[n*32 + i];
  const int co = cq * 16;
  float hb[16];
  #pragma unroll
  for (int c = 0; c < 16; ++c) hb[c] = B4[co + c];
  #pragma unroll
  for (int i = 0; i < 32; ++i){
    const float v = xi[i];
    #pragma unroll
    for (int c = 0; c < 16; ++c) hb[c] = fmaf(v, W4[i*64 + co + c], hb[c]);
  }
  const uchar* id = idx + (size_t)p * KNN;
  float ls[16], lq[16];
  #pragma unroll
  for (int c = 0; c < 16; ++c){ ls[c] = 0.f; lq[c] = 0.f; }
  for (int kk = 0; kk < 10; ++kk){
    const int j = id[kh + kk*2];
    float h[16];
    #pragma unroll
    for (int c = 0; c < 16; ++c) h[c] = hb[c];
    #pragma unroll
    for (int i = 0; i < 32; ++i){
      const float d = Xb[j*32 + i] - xi[i];
      #pragma unroll
      for (int c = 0; c < 16; ++c) h[c] = fmaf(d, W4[(32+i)*64 + co + c], h[c]);
    }
    #pragma unroll
    for (int c = 0; c < 16; ++c){ ls[c] += h[c]; lq[c] = fmaf(h[c], h[c], lq[c]); }
  }
  block_stats_span<64,16>(ls, lq, co, stat, stat + 64);
}

// ---------------- EC2 pass2: mean_k(relu(bn(h4))) then @W5 (mean-commute) ----------------
__global__ __launch_bounds__(256) void ec2_pass2(
    const float* __restrict__ x1, const uchar* __restrict__ idx,
    const float* __restrict__ W4, const float* __restrict__ B4,
    const double* __restrict__ st4, const float* __restrict__ g4, const float* __restrict__ be4,
    const float* __restrict__ W5, const float* __restrict__ B5,
    float* __restrict__ x2){
  const int t = threadIdx.x;
  const int ch = t >> 7, kh = t & 1, pl = (t >> 1) & 63;
  const int p = blockIdx.x*64 + pl;
  const int b = p >> 7, n = p & 127;
  __shared__ float sc4l[64], sh4l[64];
  __shared__ float mlds[64][65];
  if (t < 64){
    const double m = st4[t]*INVN, v = st4[64+t]*INVN - m*m;
    const float s = (float)((double)g4[t] / sqrt(v + 1e-5));
    sc4l[t] = s; sh4l[t] = be4[t] - (float)m * s;
  }
  __syncthreads();
  const float* Xb = x1 + (size_t)b * 128 * 32;
  float xi[32];
  #pragma unroll
  for (int i = 0; i < 32; ++i) xi[i] = Xb[n*32 + i];
  const int co = ch * 32;
  float hb[32];
  #pragma unroll
  for (int c = 0; c < 32; ++c) hb[c] = B4[co + c];
  #pragma unroll
  for (int i = 0; i < 32; ++i){
    const float v = xi[i];
    #pragma unroll
    for (int c = 0; c < 32; ++c) hb[c] = fmaf(v, W4[i*64 + co + c], hb[c]);
  }
  const uchar* id = idx + (size_t)p * KNN;
  float macc[32];
  #pragma unroll
  for (int c = 0; c < 32; ++c) macc[c] = 0.f;
  for (int kk = 0; kk < 10; ++kk){
    const int j = id[kh + kk*2];
    float h[32];
    #pragma unroll
    for (int c = 0; c < 32; ++c) h[c] = hb[c];
    #pragma unroll
    for (int i = 0; i < 32; ++i){
      const float d = Xb[j*32 + i] - xi[i];
      #pragma unroll
      for (int c = 0; c < 32; ++c) h[c] = fmaf(d, W4[(32+i)*64 + co + c], h[c]);
    }
    #pragma unroll
    for (int c = 0; c < 32; ++c) macc[c] += fmaxf(fmaf(h[c], sc4l[co+c], sh4l[co+c]), 0.f);
  }
  #pragma unroll
  for (int c = 0; c < 32; ++c) macc[c] += __shfl_xor(macc[c], 1, 64);  // fold k-halves
  if (kh == 0){
    #pragma unroll
    for (int c = 0; c < 32; ++c) mlds[pl][co + c] = macc[c] * (1.0f/KNN);
  }
  __syncthreads();
  // W5 phase: wave w -> output cols [w*16, w*16+16), lane = point
  const int w = t >> 6, nl2 = t & 63;
  const int pt = blockIdx.x*64 + nl2;
  float o16[16];
  #pragma unroll
  for (int c = 0; c < 16; ++c) o16[c] = B5[w*16 + c];
  #pragma unroll
  for (int i = 0; i < 64; ++i){
    const float v = mlds[nl2][i];
    #pragma unroll
    for (int c = 0; c < 16; ++c) o16[c] = fmaf(v, W5[i*64 + w*16 + c], o16[c]);
  }
  float* o = x2 + (size_t)pt*64 + w*16;
  #pragma unroll
  for (int c = 0; c < 16; ++c) o[c] = o16[c];
}

// ---------------- global max over N + head MLP ----------------
__global__ __launch_bounds__(128) void head_kernel(const float* __restrict__ x2,
    const float* __restrict__ w1, const float* __restrict__ b1,
    const float* __restrict__ w2, const float* __restrict__ b2,
    const float* __restrict__ w3, const float* __restrict__ b3,
    float* __restrict__ out){
  const int b = blockIdx.x, t = threadIdx.x;
  __shared__ float gmax[64];
  __shared__ float h1s[128];
  __shared__ float part[2];
  if (t < 64){
    const float* xb = x2 + (size_t)b * NPTS * 64 + t;
    float m = -3.0e38f;
    for (int n = 0; n < NPTS; ++n) m = fmaxf(m, xb[n*64]);
    gmax[t] = m;
  }
  __syncthreads();
  float a = b1[t];
  #pragma unroll
  for (int i = 0; i < 64; ++i) a = fmaf(gmax[i], w1[i*128 + t], a);
  h1s[t] = fmaxf(a, 0.f);
  __syncthreads();
  float h2 = b2[t];
  #pragma unroll
  for (int i = 0; i < 128; ++i) h2 = fmaf(h1s[i], w2[i*128 + t], h2);
  h2 = fmaxf(h2, 0.f);
  float pr = h2 * w3[t];
  #pragma unroll
  for (int m = 32; m; m >>= 1) pr += __shfl_xor(pr, m, 64);
  if ((t & 63) == 0) part[t >> 6] = pr;
  __syncthreads();
  if (t == 0) out[b] = part[0] + part[1] + b3[0];
}

extern "C" void kernel_launch(void* const* d_in, const int* in_sizes, int n_in,
                              void* d_out, int out_size, void* d_ws, size_t ws_size,
                              hipStream_t stream) {
  const float* points = (const float*)d_in[0];
  const float* feat   = (const float*)d_in[1];
  const float* c1_w1  = (const float*)d_in[2];
  const float* c1_b1  = (const float*)d_in[3];
  const float* c1_g1  = (const float*)d_in[4];
  const float* c1_be1 = (const float*)d_in[5];
  const float* c1_w2  = (const float*)d_in[6];
  const float* c1_b2  = (const float*)d_in[7];
  const float* c1_g2  = (const float*)d_in[8];
  const float* c1_be2 = (const float*)d_in[9];
  const float* c1_w3  = (const float*)d_in[10];
  const float* c1_b3  = (const float*)d_in[11];
  const float* c2_w1  = (const float*)d_in[12];
  const float* c2_b1  = (const float*)d_in[13];
  const float* c2_g1  = (const float*)d_in[14];
  const float* c2_be1 = (const float*)d_in[15];
  const float* c2_w2  = (const float*)d_in[16];
  const float* c2_b2  = (const float*)d_in[17];
  const float* m_w1   = (const float*)d_in[18];
  const float* m_b1   = (const float*)d_in[19];
  const float* m_w2   = (const float*)d_in[20];
  const float* m_b2   = (const float*)d_in[21];
  const float* m_w3   = (const float*)d_in[22];
  const float* m_b3   = (const float*)d_in[23];
  float* out = (float*)d_out;

  char* ws = (char*)d_ws;
  const size_t NEDGE = (size_t)NBATCH * NPTS * KNN;
  uchar*  idx1 = (uchar*)ws;
  uchar*  idx2 = (uchar*)(ws + NEDGE);
  float*  x1   = (float*)(ws + 2*NEDGE);
  float*  x2   = (float*)(ws + 2*NEDGE + (size_t)NBATCH*NPTS*32*4);
  double* stats = (double*)(ws + 2*NEDGE + (size_t)NBATCH*NPTS*(32+64)*4);
  // stats layout: [h1 sum32|sq32][h2 sum32|sq32][h4 sum64|sq64]
  double* st1 = stats;
  double* st2 = stats + 64;
  double* st4 = stats + 128;

  hipMemsetAsync(stats, 0, 256*sizeof(double), stream);

  knn1_kernel<<<1024, 256, 0, stream>>>(points, idx1);
  ec1_pass1<<<1024, 256, 0, stream>>>(feat, idx1, c1_w1, c1_b1, st1);
  ec1_pass2<<<1024, 256, 0, stream>>>(feat, idx1, c1_w1, c1_b1, st1, c1_g1, c1_be1,
                                      c1_w2, c1_b2, st2);
  ec1_pass3<<<1024, 256, 0, stream>>>(feat, idx1, c1_w1, c1_b1, st1, c1_g1, c1_be1,
                                      c1_w2, c1_b2, st2, c1_g2, c1_be2, c1_w3, c1_b3, x1);
  knn2_kernel<<<1024, 256, 0, stream>>>(x1, idx2);
  ec2_pass1<<<2048, 256, 0, stream>>>(x1, idx2, c2_w1, c2_b1, st4);
  ec2_pass2<<<1024, 256, 0, stream>>>(x1, idx2, c2_w1, c2_b1, st4, c2_g1, c2_be1,
                                      c2_w2, c2_b2, x2);
  head_kernel<<<NBATCH, 128, 0, stream>>>(x2, m_w1, m_b1, m_w2, m_b2, m_w3, m_b3, out);
}

// Round 3
// 1657.075 us; speedup vs baseline: 3.3024x; 3.3024x over previous
//
#include <hip/hip_runtime.h>
#include <math.h>

#define KK 20
#define INVN (1.0 / 1310720.0)   // 1 / (B*N*K)
#define INVK (1.0f / 20.0f)

typedef unsigned char uchar;

// BN scale/shift from accumulated double sums
__device__ inline void bn_make(const double* __restrict__ st, int C,
                               const float* __restrict__ g, const float* __restrict__ be,
                               float* scl, float* shl, int c){
  const double m = st[c]*INVN, v = st[C+c]*INVN - m*m;
  const float s = (float)((double)g[c] / sqrt(v + 1e-5));
  scl[c] = s; shl[c] = be[c] - (float)m*s;
}

// wave butterfly (sums all 64 lanes' partials) -> LDS float atomics
template<int SPAN>
__device__ inline void wave_acc_lds(const float* ls, const float* lq, int co, int lane,
                                    float* ssum, float* ssq){
  #pragma unroll
  for (int c = 0; c < SPAN; ++c){
    float a = ls[c], q = lq[c];
    #pragma unroll
    for (int m = 32; m; m >>= 1){ a += __shfl_xor(a, m, 64); q += __shfl_xor(q, m, 64); }
    if (lane == 0){ atomicAdd(&ssum[co+c], a); atomicAdd(&ssq[co+c], q); }
  }
}

// rank phase shared by both KNN kernels: rows [n0, n0+64) of D, all 128 candidates.
// rank(j) = #{j' : d_j' < d_j  or (d_j'==d_j and j'<j)}  == stable top_k order.
__device__ inline void rank_rows(const float (*D)[132], int t, int b, int n0,
                                 uchar* __restrict__ idx_out){
  const int rhalf = t >> 7;     // waves 0,1 -> row rep*2 ; waves 2,3 -> rep*2+1
  const int j = t & 127;
  for (int rep = 0; rep < 32; ++rep){
    const int rr = rep*2 + rhalf;
    const float* Drow = D[rr];
    const float myd = Drow[j];
    int cnt = 0;
    #pragma unroll 8
    for (int q4 = 0; q4 < 32; ++q4){
      const float4 v = *(const float4*)&Drow[q4*4];   // broadcast read (uniform addr)
      const int j0 = q4*4;
      cnt += (v.x < myd) + ((v.x == myd) & (j0     < j));
      cnt += (v.y < myd) + ((v.y == myd) & (j0 + 1 < j));
      cnt += (v.z < myd) + ((v.z == myd) & (j0 + 2 < j));
      cnt += (v.w < myd) + ((v.w == myd) & (j0 + 3 < j));
    }
    if (cnt < KK) idx_out[((size_t)b*128 + n0 + rr)*KK + cnt] = (uchar)j;
  }
}

// ---------------- KNN on 2-D points (rank-select) ----------------
__global__ __launch_bounds__(256) void knn1_kernel(const float* __restrict__ pts,
                                                   uchar* __restrict__ idx_out){
  const int b = blockIdx.x, t = threadIdx.x;
  __shared__ float px[128], py[128], sq[128];
  __shared__ float D[64][132];
  const float* p = pts + (size_t)b * 256;
  { float v = p[t]; if (t & 1) py[t>>1] = v; else px[t>>1] = v; }
  __syncthreads();
  if (t < 128) sq[t] = px[t]*px[t] + py[t]*py[t];
  __syncthreads();
  const int r = t >> 2, cg = t & 3;
  for (int half = 0; half < 2; ++half){
    const int n = half*64 + r;
    const float xn = px[n], yn = py[n], sn = sq[n];
    for (int jj = 0; jj < 32; ++jj){
      const int j = cg + jj*4;
      float d = sn + sq[j] - 2.0f*(xn*px[j] + yn*py[j]);
      if (j == n) d = 3.0e38f;
      D[r][j] = d;
    }
    __syncthreads();
    rank_rows(D, t, b, half*64, idx_out);
    __syncthreads();
  }
}

// ---------------- KNN on 32-D features (rank-select) ----------------
__global__ __launch_bounds__(256) void knn2_kernel(const float* __restrict__ x1,
                                                   uchar* __restrict__ idx_out){
  const int b = blockIdx.x, t = threadIdx.x;
  __shared__ float xs[128][36];   // 16B-aligned rows, bank-spread
  __shared__ float sq[128];
  __shared__ float D[64][132];
  const float* xb = x1 + (size_t)b * 4096;
  for (int i4 = t; i4 < 1024; i4 += 256){
    const float4 v = *(const float4*)&xb[i4*4];
    *(float4*)&xs[i4>>3][(i4&7)*4] = v;
  }
  __syncthreads();
  if (t < 128){
    float s = 0.f;
    #pragma unroll
    for (int c = 0; c < 32; ++c){ const float v = xs[t][c]; s = fmaf(v, v, s); }
    sq[t] = s;
  }
  __syncthreads();
  const int r = t >> 2, cg = t & 3;
  for (int half = 0; half < 2; ++half){
    const int n = half*64 + r;
    float xt[32];
    #pragma unroll
    for (int c4 = 0; c4 < 8; ++c4){
      const float4 v = *(const float4*)&xs[n][c4*4];
      xt[c4*4+0]=v.x; xt[c4*4+1]=v.y; xt[c4*4+2]=v.z; xt[c4*4+3]=v.w;
    }
    const float sn = sq[n];
    for (int jj = 0; jj < 32; ++jj){
      const int j = cg + jj*4;
      float dot = 0.f;
      #pragma unroll
      for (int c4 = 0; c4 < 8; ++c4){
        const float4 v = *(const float4*)&xs[j][c4*4];
        dot = fmaf(xt[c4*4+0], v.x, dot);
        dot = fmaf(xt[c4*4+1], v.y, dot);
        dot = fmaf(xt[c4*4+2], v.z, dot);
        dot = fmaf(xt[c4*4+3], v.w, dot);
      }
      float d = sn + sq[j] - 2.0f*dot;
      if (j == n) d = 3.0e38f;
      D[r][j] = d;
    }
    __syncthreads();
    rank_rows(D, t, b, half*64, idx_out);
    __syncthreads();
  }
}

// ---------------- EC1 stats of h1: block=64pts, waves=(ch-half,k-half) ----------------
__global__ __launch_bounds__(256) void ec1_s1(const float* __restrict__ feat,
    const uchar* __restrict__ idx, const float* __restrict__ W1, const float* __restrict__ B1,
    double* __restrict__ stat){
  const int t = threadIdx.x;
  __shared__ float xsf[128][20];
  __shared__ float ssum[32], ssq[32];
  const int p0 = blockIdx.x * 64;
  const int bb = p0 >> 7, base = p0 & 127;
  const float* fb = feat + (size_t)bb * 2048;
  for (int i4 = t; i4 < 512; i4 += 256){
    const float4 v = *(const float4*)&fb[i4*4];
    *(float4*)&xsf[i4>>2][(i4&3)*4] = v;
  }
  if (t < 32){ ssum[t] = 0.f; ssq[t] = 0.f; }
  __syncthreads();
  const int w = t >> 6, lane = t & 63;
  const int chv = __builtin_amdgcn_readfirstlane((w >> 1) * 16);
  const int kh = w & 1;
  const int nl = base + lane;
  float xi[16];
  #pragma unroll
  for (int c4 = 0; c4 < 4; ++c4){
    const float4 v = *(const float4*)&xsf[nl][c4*4];
    xi[c4*4+0]=v.x; xi[c4*4+1]=v.y; xi[c4*4+2]=v.z; xi[c4*4+3]=v.w;
  }
  float hb[16];
  #pragma unroll
  for (int c = 0; c < 16; ++c) hb[c] = B1[chv + c];
  #pragma unroll
  for (int i = 0; i < 16; ++i){
    const float v = xi[i];
    #pragma unroll
    for (int c = 0; c < 16; ++c) hb[c] = fmaf(v, W1[i*32 + chv + c], hb[c]);
  }
  const uchar* id = idx + (size_t)(p0 + lane) * KK;
  float ls[16], lq[16];
  #pragma unroll
  for (int c = 0; c < 16; ++c){ ls[c] = 0.f; lq[c] = 0.f; }
  for (int kk = 0; kk < 10; ++kk){
    const int j = id[kh + kk*2];
    float h[16];
    #pragma unroll
    for (int c = 0; c < 16; ++c) h[c] = hb[c];
    #pragma unroll
    for (int i4 = 0; i4 < 4; ++i4){
      const float4 vj = *(const float4*)&xsf[j][i4*4];
      const float d0 = vj.x - xi[i4*4+0], d1 = vj.y - xi[i4*4+1];
      const float d2 = vj.z - xi[i4*4+2], d3 = vj.w - xi[i4*4+3];
      #pragma unroll
      for (int c = 0; c < 16; ++c){
        h[c] = fmaf(d0, W1[(16+i4*4+0)*32 + chv + c], h[c]);
        h[c] = fmaf(d1, W1[(16+i4*4+1)*32 + chv + c], h[c]);
        h[c] = fmaf(d2, W1[(16+i4*4+2)*32 + chv + c], h[c]);
        h[c] = fmaf(d3, W1[(16+i4*4+3)*32 + chv + c], h[c]);
      }
    }
    #pragma unroll
    for (int c = 0; c < 16; ++c){ ls[c] += h[c]; lq[c] = fmaf(h[c], h[c], lq[c]); }
  }
  wave_acc_lds<16>(ls, lq, chv, lane, ssum, ssq);
  __syncthreads();
  if (t < 32){
    unsafeAtomicAdd(&stat[t],      (double)ssum[t]);
    unsafeAtomicAdd(&stat[32 + t], (double)ssq[t]);
  }
}

// ---------------- EC1 stats of h2 (recompute h1) ----------------
__global__ __launch_bounds__(256) void ec1_s2(const float* __restrict__ feat,
    const uchar* __restrict__ idx, const float* __restrict__ W1, const float* __restrict__ B1,
    const double* __restrict__ st1, const float* __restrict__ g1, const float* __restrict__ be1,
    const float* __restrict__ W2, const float* __restrict__ B2,
    double* __restrict__ stat){
  const int t = threadIdx.x;
  __shared__ float xsf[128][20];
  __shared__ float sc1l[32], sh1l[32];
  __shared__ float ssum[32], ssq[32];
  const int p0 = blockIdx.x * 64;
  const int bb = p0 >> 7, base = p0 & 127;
  const float* fb = feat + (size_t)bb * 2048;
  for (int i4 = t; i4 < 512; i4 += 256){
    const float4 v = *(const float4*)&fb[i4*4];
    *(float4*)&xsf[i4>>2][(i4&3)*4] = v;
  }
  if (t < 32){ ssum[t] = 0.f; ssq[t] = 0.f; bn_make(st1, 32, g1, be1, sc1l, sh1l, t); }
  __syncthreads();
  const int w = t >> 6, lane = t & 63;
  const int chv = __builtin_amdgcn_readfirstlane((w >> 1) * 16);
  const int kh = w & 1;
  const int nl = base + lane;
  float xi[16];
  #pragma unroll
  for (int c4 = 0; c4 < 4; ++c4){
    const float4 v = *(const float4*)&xsf[nl][c4*4];
    xi[c4*4+0]=v.x; xi[c4*4+1]=v.y; xi[c4*4+2]=v.z; xi[c4*4+3]=v.w;
  }
  float hb[32];
  #pragma unroll
  for (int c = 0; c < 32; ++c) hb[c] = B1[c];
  #pragma unroll
  for (int i = 0; i < 16; ++i){
    const float v = xi[i];
    #pragma unroll
    for (int c = 0; c < 32; ++c) hb[c] = fmaf(v, W1[i*32 + c], hb[c]);
  }
  const uchar* id = idx + (size_t)(p0 + lane) * KK;
  float ls[16], lq[16];
  #pragma unroll
  for (int c = 0; c < 16; ++c){ ls[c] = 0.f; lq[c] = 0.f; }
  for (int kk = 0; kk < 10; ++kk){
    const int j = id[kh + kk*2];
    float h[32];
    #pragma unroll
    for (int c = 0; c < 32; ++c) h[c] = hb[c];
    #pragma unroll
    for (int i4 = 0; i4 < 4; ++i4){
      const float4 vj = *(const float4*)&xsf[j][i4*4];
      const float dd[4] = { vj.x - xi[i4*4+0], vj.y - xi[i4*4+1],
                            vj.z - xi[i4*4+2], vj.w - xi[i4*4+3] };
      #pragma unroll
      for (int u = 0; u < 4; ++u){
        const float d = dd[u];
        #pragma unroll
        for (int c = 0; c < 32; ++c) h[c] = fmaf(d, W1[(16+i4*4+u)*32 + c], h[c]);
      }
    }
    #pragma unroll
    for (int c = 0; c < 32; ++c) h[c] = fmaxf(fmaf(h[c], sc1l[c], sh1l[c]), 0.f);
    float h2[16];
    #pragma unroll
    for (int c = 0; c < 16; ++c) h2[c] = B2[chv + c];
    #pragma unroll
    for (int i = 0; i < 32; ++i){
      const float v = h[i];
      #pragma unroll
      for (int c = 0; c < 16; ++c) h2[c] = fmaf(v, W2[i*32 + chv + c], h2[c]);
    }
    #pragma unroll
    for (int c = 0; c < 16; ++c){ ls[c] += h2[c]; lq[c] = fmaf(h2[c], h2[c], lq[c]); }
  }
  wave_acc_lds<16>(ls, lq, chv, lane, ssum, ssq);
  __syncthreads();
  if (t < 32){
    unsafeAtomicAdd(&stat[t],      (double)ssum[t]);
    unsafeAtomicAdd(&stat[32 + t], (double)ssq[t]);
  }
}

// ---------------- EC1: mean_k(relu(bn2(h2))) then @W3+B3 -> x1 ----------------
__global__ __launch_bounds__(256) void ec1_m(const float* __restrict__ feat,
    const uchar* __restrict__ idx, const float* __restrict__ W1, const float* __restrict__ B1,
    const double* __restrict__ st1, const float* __restrict__ g1, const float* __restrict__ be1,
    const float* __restrict__ W2, const float* __restrict__ B2,
    const double* __restrict__ st2, const float* __restrict__ g2, const float* __restrict__ be2,
    const float* __restrict__ W3, const float* __restrict__ B3,
    float* __restrict__ x1){
  const int t = threadIdx.x;
  __shared__ float xsf[128][20];
  __shared__ float sc1l[32], sh1l[32], sc2l[32], sh2l[32];
  __shared__ float mlds[64][33];
  const int p0 = blockIdx.x * 64;
  const int bb = p0 >> 7, base = p0 & 127;
  const float* fb = feat + (size_t)bb * 2048;
  for (int i4 = t; i4 < 512; i4 += 256){
    const float4 v = *(const float4*)&fb[i4*4];
    *(float4*)&xsf[i4>>2][(i4&3)*4] = v;
  }
  if (t < 32)            bn_make(st1, 32, g1, be1, sc1l, sh1l, t);
  else if (t < 64)       bn_make(st2, 32, g2, be2, sc2l, sh2l, t - 32);
  for (int i = t; i < 64*33; i += 256) ((float*)mlds)[i] = 0.f;
  __syncthreads();
  const int w = t >> 6, lane = t & 63;
  const int chv = __builtin_amdgcn_readfirstlane((w >> 1) * 16);
  const int kh = w & 1;
  const int nl = base + lane;
  float xi[16];
  #pragma unroll
  for (int c4 = 0; c4 < 4; ++c4){
    const float4 v = *(const float4*)&xsf[nl][c4*4];
    xi[c4*4+0]=v.x; xi[c4*4+1]=v.y; xi[c4*4+2]=v.z; xi[c4*4+3]=v.w;
  }
  float hb[32];
  #pragma unroll
  for (int c = 0; c < 32; ++c) hb[c] = B1[c];
  #pragma unroll
  for (int i = 0; i < 16; ++i){
    const float v = xi[i];
    #pragma unroll
    for (int c = 0; c < 32; ++c) hb[c] = fmaf(v, W1[i*32 + c], hb[c]);
  }
  const uchar* id = idx + (size_t)(p0 + lane) * KK;
  float macc[16];
  #pragma unroll
  for (int c = 0; c < 16; ++c) macc[c] = 0.f;
  for (int kk = 0; kk < 10; ++kk){
    const int j = id[kh + kk*2];
    float h[32];
    #pragma unroll
    for (int c = 0; c < 32; ++c) h[c] = hb[c];
    #pragma unroll
    for (int i4 = 0; i4 < 4; ++i4){
      const float4 vj = *(const float4*)&xsf[j][i4*4];
      const float dd[4] = { vj.x - xi[i4*4+0], vj.y - xi[i4*4+1],
                            vj.z - xi[i4*4+2], vj.w - xi[i4*4+3] };
      #pragma unroll
      for (int u = 0; u < 4; ++u){
        const float d = dd[u];
        #pragma unroll
        for (int c = 0; c < 32; ++c) h[c] = fmaf(d, W1[(16+i4*4+u)*32 + c], h[c]);
      }
    }
    #pragma unroll
    for (int c = 0; c < 32; ++c) h[c] = fmaxf(fmaf(h[c], sc1l[c], sh1l[c]), 0.f);
    float h2[16];
    #pragma unroll
    for (int c = 0; c < 16; ++c) h2[c] = B2[chv + c];
    #pragma unroll
    for (int i = 0; i < 32; ++i){
      const float v = h[i];
      #pragma unroll
      for (int c = 0; c < 16; ++c) h2[c] = fmaf(v, W2[i*32 + chv + c], h2[c]);
    }
    #pragma unroll
    for (int c = 0; c < 16; ++c) macc[c] += fmaxf(fmaf(h2[c], sc2l[chv+c], sh2l[chv+c]), 0.f);
  }
  #pragma unroll
  for (int c = 0; c < 16; ++c) atomicAdd(&mlds[lane][chv + c], macc[c] * INVK);
  __syncthreads();
  // W3 phase: wave -> 8 output cols, lane -> point
  const int og = __builtin_amdgcn_readfirstlane((t >> 6) * 8);
  const int pt = t & 63;
  float o8[8];
  #pragma unroll
  for (int c = 0; c < 8; ++c) o8[c] = B3[og + c];
  #pragma unroll
  for (int i = 0; i < 32; ++i){
    const float v = mlds[pt][i];
    #pragma unroll
    for (int c = 0; c < 8; ++c) o8[c] = fmaf(v, W3[i*32 + og + c], o8[c]);
  }
  float* o = x1 + (size_t)(p0 + pt) * 32 + og;
  *(float4*)&o[0] = make_float4(o8[0], o8[1], o8[2], o8[3]);
  *(float4*)&o[4] = make_float4(o8[4], o8[5], o8[6], o8[7]);
}

// ---------------- EC2 stats of h4: block=32pts, waves=ch-quarter, lane=(pt,ksub) ----------------
__global__ __launch_bounds__(256) void ec2_s(const float* __restrict__ x1,
    const uchar* __restrict__ idx, const float* __restrict__ W4, const float* __restrict__ B4,
    double* __restrict__ stat){
  const int t = threadIdx.x;
  __shared__ float xs[128][36];
  __shared__ float ssum[64], ssq[64];
  const int p0 = blockIdx.x * 32;
  const int bb = p0 >> 7, base = p0 & 127;
  const float* xb = x1 + (size_t)bb * 4096;
  for (int i4 = t; i4 < 1024; i4 += 256){
    const float4 v = *(const float4*)&xb[i4*4];
    *(float4*)&xs[i4>>3][(i4&7)*4] = v;
  }
  if (t < 64){ ssum[t] = 0.f; ssq[t] = 0.f; }
  __syncthreads();
  const int w = t >> 6, lane = t & 63;
  const int cq = __builtin_amdgcn_readfirstlane(w * 16);
  const int pl = lane & 31, ks = lane >> 5;
  const int nl = base + pl;
  float xi[32];
  #pragma unroll
  for (int c4 = 0; c4 < 8; ++c4){
    const float4 v = *(const float4*)&xs[nl][c4*4];
    xi[c4*4+0]=v.x; xi[c4*4+1]=v.y; xi[c4*4+2]=v.z; xi[c4*4+3]=v.w;
  }
  float hb[16];
  #pragma unroll
  for (int c = 0; c < 16; ++c) hb[c] = B4[cq + c];
  #pragma unroll
  for (int i = 0; i < 32; ++i){
    const float v = xi[i];
    #pragma unroll
    for (int c = 0; c < 16; ++c) hb[c] = fmaf(v, W4[i*64 + cq + c], hb[c]);
  }
  const uchar* id = idx + (size_t)(p0 + pl) * KK;
  float ls[16], lq[16];
  #pragma unroll
  for (int c = 0; c < 16; ++c){ ls[c] = 0.f; lq[c] = 0.f; }
  for (int kk = 0; kk < 10; ++kk){
    const int j = id[ks + kk*2];
    float h[16];
    #pragma unroll
    for (int c = 0; c < 16; ++c) h[c] = hb[c];
    #pragma unroll
    for (int i4 = 0; i4 < 8; ++i4){
      const float4 vj = *(const float4*)&xs[j][i4*4];
      const float dd[4] = { vj.x - xi[i4*4+0], vj.y - xi[i4*4+1],
                            vj.z - xi[i4*4+2], vj.w - xi[i4*4+3] };
      #pragma unroll
      for (int u = 0; u < 4; ++u){
        const float d = dd[u];
        #pragma unroll
        for (int c = 0; c < 16; ++c) h[c] = fmaf(d, W4[(32+i4*4+u)*64 + cq + c], h[c]);
      }
    }
    #pragma unroll
    for (int c = 0; c < 16; ++c){ ls[c] += h[c]; lq[c] = fmaf(h[c], h[c], lq[c]); }
  }
  wave_acc_lds<16>(ls, lq, cq, lane, ssum, ssq);
  __syncthreads();
  if (t < 64){
    unsafeAtomicAdd(&stat[t],      (double)ssum[t]);
    unsafeAtomicAdd(&stat[64 + t], (double)ssq[t]);
  }
}

// ---------------- EC2: mean_k(relu(bn4(h4))) then @W5+B5 -> x2 ----------------
__global__ __launch_bounds__(256) void ec2_m(const float* __restrict__ x1,
    const uchar* __restrict__ idx, const float* __restrict__ W4, const float* __restrict__ B4,
    const double* __restrict__ st4, const float* __restrict__ g4, const float* __restrict__ be4,
    const float* __restrict__ W5, const float* __restrict__ B5,
    float* __restrict__ x2){
  const int t = threadIdx.x;
  __shared__ float xs[128][36];
  __shared__ float sc4l[64], sh4l[64];
  __shared__ float mlds[64][65];
  const int p0 = blockIdx.x * 64;
  const int bb = p0 >> 7, base = p0 & 127;
  const float* xb = x1 + (size_t)bb * 4096;
  for (int i4 = t; i4 < 1024; i4 += 256){
    const float4 v = *(const float4*)&xb[i4*4];
    *(float4*)&xs[i4>>3][(i4&7)*4] = v;
  }
  if (t < 64) bn_make(st4, 64, g4, be4, sc4l, sh4l, t);
  for (int i = t; i < 64*65; i += 256) ((float*)mlds)[i] = 0.f;
  __syncthreads();
  const int w = t >> 6, lane = t & 63;
  const int chv = __builtin_amdgcn_readfirstlane((w >> 1) * 32);
  const int kh = w & 1;
  const int nl = base + lane;
  float xi[32];
  #pragma unroll
  for (int c4 = 0; c4 < 8; ++c4){
    const float4 v = *(const float4*)&xs[nl][c4*4];
    xi[c4*4+0]=v.x; xi[c4*4+1]=v.y; xi[c4*4+2]=v.z; xi[c4*4+3]=v.w;
  }
  float hb[32];
  #pragma unroll
  for (int c = 0; c < 32; ++c) hb[c] = B4[chv + c];
  #pragma unroll
  for (int i = 0; i < 32; ++i){
    const float v = xi[i];
    #pragma unroll
    for (int c = 0; c < 32; ++c) hb[c] = fmaf(v, W4[i*64 + chv + c], hb[c]);
  }
  const uchar* id = idx + (size_t)(p0 + lane) * KK;
  float macc[32];
  #pragma unroll
  for (int c = 0; c < 32; ++c) macc[c] = 0.f;
  for (int kk = 0; kk < 10; ++kk){
    const int j = id[kh + kk*2];
    float h[32];
    #pragma unroll
    for (int c = 0; c < 32; ++c) h[c] = hb[c];
    #pragma unroll
    for (int i4 = 0; i4 < 8; ++i4){
      const float4 vj = *(const float4*)&xs[j][i4*4];
      const float dd[4] = { vj.x - xi[i4*4+0], vj.y - xi[i4*4+1],
                            vj.z - xi[i4*4+2], vj.w - xi[i4*4+3] };
      #pragma unroll
      for (int u = 0; u < 4; ++u){
        const float d = dd[u];
        #pragma unroll
        for (int c = 0; c < 32; ++c) h[c] = fmaf(d, W4[(32+i4*4+u)*64 + chv + c], h[c]);
      }
    }
    #pragma unroll
    for (int c = 0; c < 32; ++c) macc[c] += fmaxf(fmaf(h[c], sc4l[chv+c], sh4l[chv+c]), 0.f);
  }
  #pragma unroll
  for (int c = 0; c < 32; ++c) atomicAdd(&mlds[lane][chv + c], macc[c] * INVK);
  __syncthreads();
  // W5 phase: wave -> 16 output cols, lane -> point
  const int og = __builtin_amdgcn_readfirstlane((t >> 6) * 16);
  const int pt = t & 63;
  float o16[16];
  #pragma unroll
  for (int c = 0; c < 16; ++c) o16[c] = B5[og + c];
  #pragma unroll
  for (int i = 0; i < 64; ++i){
    const float v = mlds[pt][i];
    #pragma unroll
    for (int c = 0; c < 16; ++c) o16[c] = fmaf(v, W5[i*64 + og + c], o16[c]);
  }
  float* o = x2 + (size_t)(p0 + pt) * 64 + og;
  #pragma unroll
  for (int c4 = 0; c4 < 4; ++c4)
    *(float4*)&o[c4*4] = make_float4(o16[c4*4], o16[c4*4+1], o16[c4*4+2], o16[c4*4+3]);
}

// ---------------- global max over N + head MLP ----------------
__global__ __launch_bounds__(128) void head_kernel(const float* __restrict__ x2,
    const float* __restrict__ w1, const float* __restrict__ b1,
    const float* __restrict__ w2, const float* __restrict__ b2,
    const float* __restrict__ w3, const float* __restrict__ b3,
    float* __restrict__ out){
  const int b = blockIdx.x, t = threadIdx.x;
  __shared__ float gmax[64];
  __shared__ float h1s[128];
  __shared__ float part[2];
  if (t < 64){
    const float* xb = x2 + (size_t)b * 128 * 64 + t;
    float m = -3.0e38f;
    for (int n = 0; n < 128; ++n) m = fmaxf(m, xb[n*64]);
    gmax[t] = m;
  }
  __syncthreads();
  float a = b1[t];
  #pragma unroll
  for (int i = 0; i < 64; ++i) a = fmaf(gmax[i], w1[i*128 + t], a);
  h1s[t] = fmaxf(a, 0.f);
  __syncthreads();
  float h2 = b2[t];
  #pragma unroll
  for (int i = 0; i < 128; ++i) h2 = fmaf(h1s[i], w2[i*128 + t], h2);
  h2 = fmaxf(h2, 0.f);
  float pr = h2 * w3[t];
  #pragma unroll
  for (int m = 32; m; m >>= 1) pr += __shfl_xor(pr, m, 64);
  if ((t & 63) == 0) part[t >> 6] = pr;
  __syncthreads();
  if (t == 0) out[b] = part[0] + part[1] + b3[0];
}

extern "C" void kernel_launch(void* const* d_in, const int* in_sizes, int n_in,
                              void* d_out, int out_size, void* d_ws, size_t ws_size,
                              hipStream_t stream) {
  const float* points = (const float*)d_in[0];
  const float* feat   = (const float*)d_in[1];
  const float* c1_w1  = (const float*)d_in[2];
  const float* c1_b1  = (const float*)d_in[3];
  const float* c1_g1  = (const float*)d_in[4];
  const float* c1_be1 = (const float*)d_in[5];
  const float* c1_w2  = (const float*)d_in[6];
  const float* c1_b2  = (const float*)d_in[7];
  const float* c1_g2  = (const float*)d_in[8];
  const float* c1_be2 = (const float*)d_in[9];
  const float* c1_w3  = (const float*)d_in[10];
  const float* c1_b3  = (const float*)d_in[11];
  const float* c2_w1  = (const float*)d_in[12];
  const float* c2_b1  = (const float*)d_in[13];
  const float* c2_g1  = (const float*)d_in[14];
  const float* c2_be1 = (const float*)d_in[15];
  const float* c2_w2  = (const float*)d_in[16];
  const float* c2_b2  = (const float*)d_in[17];
  const float* m_w1   = (const float*)d_in[18];
  const float* m_b1   = (const float*)d_in[19];
  const float* m_w2   = (const float*)d_in[20];
  const float* m_b2   = (const float*)d_in[21];
  const float* m_w3   = (const float*)d_in[22];
  const float* m_b3   = (const float*)d_in[23];
  float* out = (float*)d_out;

  char* ws = (char*)d_ws;
  const size_t NEDGE = (size_t)512 * 128 * KK;   // 1,310,720
  uchar*  idx1 = (uchar*)ws;
  uchar*  idx2 = (uchar*)(ws + NEDGE);
  float*  x1   = (float*)(ws + 2*NEDGE);                              // 8.39 MB
  float*  x2   = (float*)(ws + 2*NEDGE + (size_t)65536*32*4);         // 16.8 MB
  double* stats = (double*)(ws + 2*NEDGE + (size_t)65536*96*4);
  double* st1 = stats;         // [sum32 | sq32]
  double* st2 = stats + 64;    // [sum32 | sq32]
  double* st4 = stats + 128;   // [sum64 | sq64]

  hipMemsetAsync(stats, 0, 256*sizeof(double), stream);

  knn1_kernel<<<512, 256, 0, stream>>>(points, idx1);
  ec1_s1<<<1024, 256, 0, stream>>>(feat, idx1, c1_w1, c1_b1, st1);
  ec1_s2<<<1024, 256, 0, stream>>>(feat, idx1, c1_w1, c1_b1, st1, c1_g1, c1_be1,
                                   c1_w2, c1_b2, st2);
  ec1_m<<<1024, 256, 0, stream>>>(feat, idx1, c1_w1, c1_b1, st1, c1_g1, c1_be1,
                                  c1_w2, c1_b2, st2, c1_g2, c1_be2, c1_w3, c1_b3, x1);
  knn2_kernel<<<512, 256, 0, stream>>>(x1, idx2);
  ec2_s<<<2048, 256, 0, stream>>>(x1, idx2, c2_w1, c2_b1, st4);
  ec2_m<<<1024, 256, 0, stream>>>(x1, idx2, c2_w1, c2_b1, st4, c2_g1, c2_be1,
                                  c2_w2, c2_b2, x2);
  head_kernel<<<512, 128, 0, stream>>>(x2, m_w1, m_b1, m_w2, m_b2, m_w3, m_b3, out);
}

// Round 4
// 1357.040 us; speedup vs baseline: 4.0325x; 1.2211x over previous
//
#include <hip/hip_runtime.h>
#include <math.h>

#define KK 20
#define INVN (1.0 / 1310720.0)   // 1 / (B*N*K)
#define INVK (1.0f / 20.0f)

typedef unsigned char uchar;
typedef unsigned int uint;

// BN scale/shift from accumulated double sums
__device__ inline void bn_make(const double* __restrict__ st, int C,
                               const float* __restrict__ g, const float* __restrict__ be,
                               float* scl, float* shl, int c){
  const double m = st[c]*INVN, v = st[C+c]*INVN - m*m;
  const float s = (float)((double)g[c] / sqrt(v + 1e-5));
  scl[c] = s; shl[c] = be[c] - (float)m*s;
}

// rank phase shared by both KNN kernels (stable top_k semantics)
__device__ inline void rank_rows(const float (*D)[132], int t, int b, int n0,
                                 uchar* __restrict__ idx_out){
  const int rhalf = t >> 7;
  const int j = t & 127;
  for (int rep = 0; rep < 32; ++rep){
    const int rr = rep*2 + rhalf;
    const float* Drow = D[rr];
    const float myd = Drow[j];
    int cnt = 0;
    #pragma unroll 8
    for (int q4 = 0; q4 < 32; ++q4){
      const float4 v = *(const float4*)&Drow[q4*4];
      const int j0 = q4*4;
      cnt += (v.x < myd) + ((v.x == myd) & (j0     < j));
      cnt += (v.y < myd) + ((v.y == myd) & (j0 + 1 < j));
      cnt += (v.z < myd) + ((v.z == myd) & (j0 + 2 < j));
      cnt += (v.w < myd) + ((v.w == myd) & (j0 + 3 < j));
    }
    if (cnt < KK) idx_out[((size_t)b*128 + n0 + rr)*KK + cnt] = (uchar)j;
  }
}

// ---------------- KNN on 2-D points ----------------
__global__ __launch_bounds__(256) void knn1_kernel(const float* __restrict__ pts,
                                                   uchar* __restrict__ idx_out){
  const int b = blockIdx.x, t = threadIdx.x;
  __shared__ float px[128], py[128], sq[128];
  __shared__ float D[64][132];
  const float* p = pts + (size_t)b * 256;
  { float v = p[t]; if (t & 1) py[t>>1] = v; else px[t>>1] = v; }
  __syncthreads();
  if (t < 128) sq[t] = px[t]*px[t] + py[t]*py[t];
  __syncthreads();
  const int r = t >> 2, cg = t & 3;
  for (int half = 0; half < 2; ++half){
    const int n = half*64 + r;
    const float xn = px[n], yn = py[n], sn = sq[n];
    for (int jj = 0; jj < 32; ++jj){
      const int j = cg + jj*4;
      float d = sn + sq[j] - 2.0f*(xn*px[j] + yn*py[j]);
      if (j == n) d = 3.0e38f;
      D[r][j] = d;
    }
    __syncthreads();
    rank_rows(D, t, b, half*64, idx_out);
    __syncthreads();
  }
}

// ---------------- KNN on 32-D features ----------------
__global__ __launch_bounds__(256) void knn2_kernel(const float* __restrict__ x1,
                                                   uchar* __restrict__ idx_out){
  const int b = blockIdx.x, t = threadIdx.x;
  __shared__ float xs[128][36];
  __shared__ float sq[128];
  __shared__ float D[64][132];
  const float* xb = x1 + (size_t)b * 4096;
  for (int i4 = t; i4 < 1024; i4 += 256){
    const float4 v = *(const float4*)&xb[i4*4];
    *(float4*)&xs[i4>>3][(i4&7)*4] = v;
  }
  __syncthreads();
  if (t < 128){
    float s = 0.f;
    #pragma unroll
    for (int c = 0; c < 32; ++c){ const float v = xs[t][c]; s = fmaf(v, v, s); }
    sq[t] = s;
  }
  __syncthreads();
  const int r = t >> 2, cg = t & 3;
  for (int half = 0; half < 2; ++half){
    const int n = half*64 + r;
    float xt[32];
    #pragma unroll
    for (int c4 = 0; c4 < 8; ++c4){
      const float4 v = *(const float4*)&xs[n][c4*4];
      xt[c4*4+0]=v.x; xt[c4*4+1]=v.y; xt[c4*4+2]=v.z; xt[c4*4+3]=v.w;
    }
    const float sn = sq[n];
    for (int jj = 0; jj < 32; ++jj){
      const int j = cg + jj*4;
      float dot = 0.f;
      #pragma unroll
      for (int c4 = 0; c4 < 8; ++c4){
        const float4 v = *(const float4*)&xs[j][c4*4];
        dot = fmaf(xt[c4*4+0], v.x, dot);
        dot = fmaf(xt[c4*4+1], v.y, dot);
        dot = fmaf(xt[c4*4+2], v.z, dot);
        dot = fmaf(xt[c4*4+3], v.w, dot);
      }
      float d = sn + sq[j] - 2.0f*dot;
      if (j == n) d = 3.0e38f;
      D[r][j] = d;
    }
    __syncthreads();
    rank_rows(D, t, b, half*64, idx_out);
    __syncthreads();
  }
}

// ---------------- EC1 layer-1 stats via separability: h1(i,j)=p_i+q_j ----------------
__global__ __launch_bounds__(256) void pqs1(const float* __restrict__ feat,
    const uchar* __restrict__ idx, const float* __restrict__ W1, const float* __restrict__ B1,
    double* __restrict__ stat){
  const int t = threadIdx.x, b = blockIdx.x;
  __shared__ float Xl[128*20];
  __shared__ float W1l[32*36];
  __shared__ float Qp[128*33];
  __shared__ float ssum[32], ssq[32];
  __shared__ uint idxl[640];
  const float* fb = feat + (size_t)b*2048;
  for (int i4 = t; i4 < 512; i4 += 256){
    const float4 v = *(const float4*)&fb[i4*4];
    *(float4*)&Xl[(i4>>2)*20 + (i4&3)*4] = v;
  }
  { const float4 v = *(const float4*)&W1[t*4];
    *(float4*)&W1l[(t>>3)*36 + (t&7)*4] = v; }
  const uint* ig = (const uint*)(idx + (size_t)b*2560);
  for (int i = t; i < 640; i += 256) idxl[i] = ig[i];
  if (t < 32){ ssum[t]=0.f; ssq[t]=0.f; }
  __syncthreads();
  const int p = t & 127;
  const int c0 = __builtin_amdgcn_readfirstlane((t>>7)*16);
  float xi[16];
  #pragma unroll
  for (int c4 = 0; c4 < 4; ++c4){
    const float4 v = *(const float4*)&Xl[p*20 + c4*4];
    xi[c4*4]=v.x; xi[c4*4+1]=v.y; xi[c4*4+2]=v.z; xi[c4*4+3]=v.w;
  }
  float t1[16], qv[16];
  #pragma unroll
  for (int c = 0; c < 16; ++c){ t1[c]=0.f; qv[c]=0.f; }
  #pragma unroll
  for (int i = 0; i < 16; ++i){
    const float v = xi[i];
    #pragma unroll
    for (int c4 = 0; c4 < 4; ++c4){
      const float4 wa = *(const float4*)&W1l[i*36 + c0 + c4*4];
      const float4 wb = *(const float4*)&W1l[(16+i)*36 + c0 + c4*4];
      t1[c4*4+0]=fmaf(v,wa.x,t1[c4*4+0]); t1[c4*4+1]=fmaf(v,wa.y,t1[c4*4+1]);
      t1[c4*4+2]=fmaf(v,wa.z,t1[c4*4+2]); t1[c4*4+3]=fmaf(v,wa.w,t1[c4*4+3]);
      qv[c4*4+0]=fmaf(v,wb.x,qv[c4*4+0]); qv[c4*4+1]=fmaf(v,wb.y,qv[c4*4+1]);
      qv[c4*4+2]=fmaf(v,wb.z,qv[c4*4+2]); qv[c4*4+3]=fmaf(v,wb.w,qv[c4*4+3]);
    }
  }
  float pv[16];
  #pragma unroll
  for (int c = 0; c < 16; ++c){
    pv[c] = t1[c] - qv[c] + B1[c0+c];
    Qp[p*33 + c0 + c] = qv[c];
  }
  __syncthreads();
  const uchar* mi = (const uchar*)idxl + p*20;
  float Qs[16], Q2[16];
  #pragma unroll
  for (int c = 0; c < 16; ++c){ Qs[c]=0.f; Q2[c]=0.f; }
  for (int k = 0; k < KK; ++k){
    const int j = mi[k];
    #pragma unroll
    for (int c = 0; c < 16; ++c){
      const float q = Qp[j*33 + c0 + c];
      Qs[c] += q; Q2[c] = fmaf(q, q, Q2[c]);
    }
  }
  #pragma unroll
  for (int c = 0; c < 16; ++c){
    float a = fmaf(20.f, pv[c], Qs[c]);
    float q = fmaf(20.f*pv[c], pv[c], fmaf(2.f*pv[c], Qs[c], Q2[c]));
    #pragma unroll
    for (int m = 32; m; m >>= 1){ a += __shfl_xor(a,m,64); q += __shfl_xor(q,m,64); }
    if ((t & 63) == 0){ atomicAdd(&ssum[c0+c], a); atomicAdd(&ssq[c0+c], q); }
  }
  __syncthreads();
  if (t < 32){
    unsafeAtomicAdd(&stat[t], (double)ssum[t]);
    unsafeAtomicAdd(&stat[32+t], (double)ssq[t]);
  }
}

// ---------------- EC1 h2 stats: r=relu(P'+Q'), h2=r@W2+b2 (LDS-tiled) ----------------
__global__ __launch_bounds__(256) void ec1_s2(const float* __restrict__ feat,
    const uchar* __restrict__ idx, const float* __restrict__ W1, const float* __restrict__ B1,
    const double* __restrict__ st1, const float* __restrict__ g1, const float* __restrict__ be1,
    const float* __restrict__ W2, const float* __restrict__ B2,
    double* __restrict__ stat){
  const int t = threadIdx.x, b = blockIdx.x;
  __shared__ float Xl[128*20];
  __shared__ float W1l[32*36];
  __shared__ float W2l[32*36];
  __shared__ float Qp[128*33];
  __shared__ float Pp[128*33];
  __shared__ float sc1l[32], sh1l[32];
  __shared__ float ssum[32], ssq[32];
  __shared__ uint idxl[640];
  const float* fb = feat + (size_t)b*2048;
  for (int i4 = t; i4 < 512; i4 += 256){
    const float4 v = *(const float4*)&fb[i4*4];
    *(float4*)&Xl[(i4>>2)*20 + (i4&3)*4] = v;
  }
  { const float4 v = *(const float4*)&W1[t*4];
    *(float4*)&W1l[(t>>3)*36 + (t&7)*4] = v; }
  { const float4 v = *(const float4*)&W2[t*4];
    *(float4*)&W2l[(t>>3)*36 + (t&7)*4] = v; }
  const uint* ig = (const uint*)(idx + (size_t)b*2560);
  for (int i = t; i < 640; i += 256) idxl[i] = ig[i];
  if (t < 32){ ssum[t]=0.f; ssq[t]=0.f; bn_make(st1,32,g1,be1,sc1l,sh1l,t); }
  __syncthreads();
  const int p = t & 127;
  const int c0 = __builtin_amdgcn_readfirstlane((t>>7)*16);
  {
    float xi[16];
    #pragma unroll
    for (int c4 = 0; c4 < 4; ++c4){
      const float4 v = *(const float4*)&Xl[p*20 + c4*4];
      xi[c4*4]=v.x; xi[c4*4+1]=v.y; xi[c4*4+2]=v.z; xi[c4*4+3]=v.w;
    }
    float t1[16], qv[16];
    #pragma unroll
    for (int c = 0; c < 16; ++c){ t1[c]=0.f; qv[c]=0.f; }
    #pragma unroll
    for (int i = 0; i < 16; ++i){
      const float v = xi[i];
      #pragma unroll
      for (int c4 = 0; c4 < 4; ++c4){
        const float4 wa = *(const float4*)&W1l[i*36 + c0 + c4*4];
        const float4 wb = *(const float4*)&W1l[(16+i)*36 + c0 + c4*4];
        t1[c4*4+0]=fmaf(v,wa.x,t1[c4*4+0]); t1[c4*4+1]=fmaf(v,wa.y,t1[c4*4+1]);
        t1[c4*4+2]=fmaf(v,wa.z,t1[c4*4+2]); t1[c4*4+3]=fmaf(v,wa.w,t1[c4*4+3]);
        qv[c4*4+0]=fmaf(v,wb.x,qv[c4*4+0]); qv[c4*4+1]=fmaf(v,wb.y,qv[c4*4+1]);
        qv[c4*4+2]=fmaf(v,wb.z,qv[c4*4+2]); qv[c4*4+3]=fmaf(v,wb.w,qv[c4*4+3]);
      }
    }
    #pragma unroll
    for (int c = 0; c < 16; ++c){
      const float sc = sc1l[c0+c];
      Pp[p*33 + c0 + c] = fmaf(t1[c] - qv[c] + B1[c0+c], sc, sh1l[c0+c]);
      Qp[p*33 + c0 + c] = qv[c]*sc;
    }
  }
  __syncthreads();
  float pv[32];
  #pragma unroll
  for (int c = 0; c < 32; ++c) pv[c] = Pp[p*33 + c];
  float ls[16], lq[16];
  #pragma unroll
  for (int c = 0; c < 16; ++c){ ls[c]=0.f; lq[c]=0.f; }
  const uchar* mi = (const uchar*)idxl + p*20;
  for (int kk = 0; kk < 10; ++kk){
    const int j0 = mi[kk*2], j1 = mi[kk*2+1];
    float rA[32], rB[32];
    #pragma unroll
    for (int c = 0; c < 32; ++c){
      rA[c] = fmaxf(pv[c] + Qp[j0*33 + c], 0.f);
      rB[c] = fmaxf(pv[c] + Qp[j1*33 + c], 0.f);
    }
    float hA[16], hB[16];
    #pragma unroll
    for (int c = 0; c < 16; ++c){ const float bb = B2[c0+c]; hA[c]=bb; hB[c]=bb; }
    #pragma unroll
    for (int i = 0; i < 32; ++i){
      const float ra = rA[i], rb = rB[i];
      #pragma unroll
      for (int c4 = 0; c4 < 4; ++c4){
        const float4 w = *(const float4*)&W2l[i*36 + c0 + c4*4];
        hA[c4*4+0]=fmaf(ra,w.x,hA[c4*4+0]); hA[c4*4+1]=fmaf(ra,w.y,hA[c4*4+1]);
        hA[c4*4+2]=fmaf(ra,w.z,hA[c4*4+2]); hA[c4*4+3]=fmaf(ra,w.w,hA[c4*4+3]);
        hB[c4*4+0]=fmaf(rb,w.x,hB[c4*4+0]); hB[c4*4+1]=fmaf(rb,w.y,hB[c4*4+1]);
        hB[c4*4+2]=fmaf(rb,w.z,hB[c4*4+2]); hB[c4*4+3]=fmaf(rb,w.w,hB[c4*4+3]);
      }
    }
    #pragma unroll
    for (int c = 0; c < 16; ++c){
      ls[c] += hA[c] + hB[c];
      lq[c] = fmaf(hA[c], hA[c], lq[c]);
      lq[c] = fmaf(hB[c], hB[c], lq[c]);
    }
  }
  #pragma unroll
  for (int c = 0; c < 16; ++c){
    float a = ls[c], q = lq[c];
    #pragma unroll
    for (int m = 32; m; m >>= 1){ a += __shfl_xor(a,m,64); q += __shfl_xor(q,m,64); }
    if ((t & 63) == 0){ atomicAdd(&ssum[c0+c], a); atomicAdd(&ssq[c0+c], q); }
  }
  __syncthreads();
  if (t < 32){
    unsafeAtomicAdd(&stat[t], (double)ssum[t]);
    unsafeAtomicAdd(&stat[32+t], (double)ssq[t]);
  }
}

// ---------------- EC1 output: mean_k relu(bn2(h2)) @ W3 + b3 -> x1 ----------------
__global__ __launch_bounds__(256) void ec1_m(const float* __restrict__ feat,
    const uchar* __restrict__ idx, const float* __restrict__ W1, const float* __restrict__ B1,
    const double* __restrict__ st1, const float* __restrict__ g1, const float* __restrict__ be1,
    const float* __restrict__ W2, const float* __restrict__ B2,
    const double* __restrict__ st2, const float* __restrict__ g2, const float* __restrict__ be2,
    const float* __restrict__ W3, const float* __restrict__ B3,
    float* __restrict__ x1){
  const int t = threadIdx.x, b = blockIdx.x;
  __shared__ float Xl[128*20];
  __shared__ float W1l[32*36];
  __shared__ float W2l[32*36];   // bn2-scale folded
  __shared__ float Qp[128*33];
  __shared__ float Pp[128*33];
  __shared__ float mlds[128*33];
  __shared__ float sc1l[32], sh1l[32], sc2l[32], sh2l[32];
  __shared__ uint idxl[640];
  if (t < 32) bn_make(st1,32,g1,be1,sc1l,sh1l,t);
  else if (t < 64) bn_make(st2,32,g2,be2,sc2l,sh2l,t-32);
  __syncthreads();
  const float* fb = feat + (size_t)b*2048;
  for (int i4 = t; i4 < 512; i4 += 256){
    const float4 v = *(const float4*)&fb[i4*4];
    *(float4*)&Xl[(i4>>2)*20 + (i4&3)*4] = v;
  }
  { const float4 v = *(const float4*)&W1[t*4];
    *(float4*)&W1l[(t>>3)*36 + (t&7)*4] = v; }
  { const float4 v = *(const float4*)&W2[t*4];
    const int col = (t&7)*4;
    float4 w;
    w.x = v.x*sc2l[col]; w.y = v.y*sc2l[col+1]; w.z = v.z*sc2l[col+2]; w.w = v.w*sc2l[col+3];
    *(float4*)&W2l[(t>>3)*36 + col] = w; }
  const uint* ig = (const uint*)(idx + (size_t)b*2560);
  for (int i = t; i < 640; i += 256) idxl[i] = ig[i];
  __syncthreads();
  const int p = t & 127;
  const int c0 = __builtin_amdgcn_readfirstlane((t>>7)*16);
  {
    float xi[16];
    #pragma unroll
    for (int c4 = 0; c4 < 4; ++c4){
      const float4 v = *(const float4*)&Xl[p*20 + c4*4];
      xi[c4*4]=v.x; xi[c4*4+1]=v.y; xi[c4*4+2]=v.z; xi[c4*4+3]=v.w;
    }
    float t1[16], qv[16];
    #pragma unroll
    for (int c = 0; c < 16; ++c){ t1[c]=0.f; qv[c]=0.f; }
    #pragma unroll
    for (int i = 0; i < 16; ++i){
      const float v = xi[i];
      #pragma unroll
      for (int c4 = 0; c4 < 4; ++c4){
        const float4 wa = *(const float4*)&W1l[i*36 + c0 + c4*4];
        const float4 wb = *(const float4*)&W1l[(16+i)*36 + c0 + c4*4];
        t1[c4*4+0]=fmaf(v,wa.x,t1[c4*4+0]); t1[c4*4+1]=fmaf(v,wa.y,t1[c4*4+1]);
        t1[c4*4+2]=fmaf(v,wa.z,t1[c4*4+2]); t1[c4*4+3]=fmaf(v,wa.w,t1[c4*4+3]);
        qv[c4*4+0]=fmaf(v,wb.x,qv[c4*4+0]); qv[c4*4+1]=fmaf(v,wb.y,qv[c4*4+1]);
        qv[c4*4+2]=fmaf(v,wb.z,qv[c4*4+2]); qv[c4*4+3]=fmaf(v,wb.w,qv[c4*4+3]);
      }
    }
    #pragma unroll
    for (int c = 0; c < 16; ++c){
      const float sc = sc1l[c0+c];
      Pp[p*33 + c0 + c] = fmaf(t1[c] - qv[c] + B1[c0+c], sc, sh1l[c0+c]);
      Qp[p*33 + c0 + c] = qv[c]*sc;
    }
  }
  __syncthreads();
  float pv[32];
  #pragma unroll
  for (int c = 0; c < 32; ++c) pv[c] = Pp[p*33 + c];
  float b2v[16];
  #pragma unroll
  for (int c = 0; c < 16; ++c) b2v[c] = fmaf(B2[c0+c], sc2l[c0+c], sh2l[c0+c]);
  float macc[16];
  #pragma unroll
  for (int c = 0; c < 16; ++c) macc[c] = 0.f;
  const uchar* mi = (const uchar*)idxl + p*20;
  for (int kk = 0; kk < 10; ++kk){
    const int j0 = mi[kk*2], j1 = mi[kk*2+1];
    float rA[32], rB[32];
    #pragma unroll
    for (int c = 0; c < 32; ++c){
      rA[c] = fmaxf(pv[c] + Qp[j0*33 + c], 0.f);
      rB[c] = fmaxf(pv[c] + Qp[j1*33 + c], 0.f);
    }
    float hA[16], hB[16];
    #pragma unroll
    for (int c = 0; c < 16; ++c){ hA[c]=b2v[c]; hB[c]=b2v[c]; }
    #pragma unroll
    for (int i = 0; i < 32; ++i){
      const float ra = rA[i], rb = rB[i];
      #pragma unroll
      for (int c4 = 0; c4 < 4; ++c4){
        const float4 w = *(const float4*)&W2l[i*36 + c0 + c4*4];
        hA[c4*4+0]=fmaf(ra,w.x,hA[c4*4+0]); hA[c4*4+1]=fmaf(ra,w.y,hA[c4*4+1]);
        hA[c4*4+2]=fmaf(ra,w.z,hA[c4*4+2]); hA[c4*4+3]=fmaf(ra,w.w,hA[c4*4+3]);
        hB[c4*4+0]=fmaf(rb,w.x,hB[c4*4+0]); hB[c4*4+1]=fmaf(rb,w.y,hB[c4*4+1]);
        hB[c4*4+2]=fmaf(rb,w.z,hB[c4*4+2]); hB[c4*4+3]=fmaf(rb,w.w,hB[c4*4+3]);
      }
    }
    #pragma unroll
    for (int c = 0; c < 16; ++c)
      macc[c] += fmaxf(hA[c], 0.f) + fmaxf(hB[c], 0.f);
  }
  #pragma unroll
  for (int c = 0; c < 16; ++c) mlds[p*33 + c0 + c] = macc[c] * INVK;
  __syncthreads();
  // W3 phase: thread -> (point, 16-col group); W3 via uniform s_load
  const int pt = t & 127;
  const int og = __builtin_amdgcn_readfirstlane((t>>7)*16);
  float o16[16];
  #pragma unroll
  for (int c = 0; c < 16; ++c) o16[c] = B3[og + c];
  #pragma unroll
  for (int i = 0; i < 32; ++i){
    const float v = mlds[pt*33 + i];
    #pragma unroll
    for (int c = 0; c < 16; ++c) o16[c] = fmaf(v, W3[i*32 + og + c], o16[c]);
  }
  float* o = x1 + ((size_t)b*128 + pt)*32 + og;
  #pragma unroll
  for (int c4 = 0; c4 < 4; ++c4)
    *(float4*)&o[c4*4] = make_float4(o16[c4*4], o16[c4*4+1], o16[c4*4+2], o16[c4*4+3]);
}

// ---------------- EC2 h4 stats via separability ----------------
__global__ __launch_bounds__(256) void pqs4(const float* __restrict__ x1,
    const uchar* __restrict__ idx, const float* __restrict__ W4, const float* __restrict__ B4,
    double* __restrict__ stat){
  const int t = threadIdx.x, b = blockIdx.x;
  __shared__ float X1b[128*33];
  __shared__ float W4l[64*68];
  __shared__ float Qp4[128*65];
  __shared__ float ssum[64], ssq[64];
  __shared__ uint idxl[640];
  const float* xb = x1 + (size_t)b*4096;
  for (int i4 = t; i4 < 1024; i4 += 256){
    const float4 v = *(const float4*)&xb[i4*4];
    const int r = i4>>3, c = (i4&7)*4;
    X1b[r*33+c]=v.x; X1b[r*33+c+1]=v.y; X1b[r*33+c+2]=v.z; X1b[r*33+c+3]=v.w;
  }
  for (int i4 = t; i4 < 1024; i4 += 256){
    const float4 v = *(const float4*)&W4[i4*4];
    *(float4*)&W4l[(i4>>4)*68 + (i4&15)*4] = v;
  }
  const uint* ig = (const uint*)(idx + (size_t)b*2560);
  for (int i = t; i < 640; i += 256) idxl[i] = ig[i];
  if (t < 64){ ssum[t]=0.f; ssq[t]=0.f; }
  __syncthreads();
  const int p = t & 127;
  const int c0 = __builtin_amdgcn_readfirstlane((t>>7)*32);
  float xi[32];
  #pragma unroll
  for (int i = 0; i < 32; ++i) xi[i] = X1b[p*33 + i];
  float t1[32], qv[32];
  #pragma unroll
  for (int c = 0; c < 32; ++c){ t1[c]=0.f; qv[c]=0.f; }
  #pragma unroll
  for (int i = 0; i < 32; ++i){
    const float v = xi[i];
    #pragma unroll
    for (int c4 = 0; c4 < 8; ++c4){
      const float4 wa = *(const float4*)&W4l[i*68 + c0 + c4*4];
      const float4 wb = *(const float4*)&W4l[(32+i)*68 + c0 + c4*4];
      t1[c4*4+0]=fmaf(v,wa.x,t1[c4*4+0]); t1[c4*4+1]=fmaf(v,wa.y,t1[c4*4+1]);
      t1[c4*4+2]=fmaf(v,wa.z,t1[c4*4+2]); t1[c4*4+3]=fmaf(v,wa.w,t1[c4*4+3]);
      qv[c4*4+0]=fmaf(v,wb.x,qv[c4*4+0]); qv[c4*4+1]=fmaf(v,wb.y,qv[c4*4+1]);
      qv[c4*4+2]=fmaf(v,wb.z,qv[c4*4+2]); qv[c4*4+3]=fmaf(v,wb.w,qv[c4*4+3]);
    }
  }
  float pv[32];
  #pragma unroll
  for (int c = 0; c < 32; ++c){
    pv[c] = t1[c] - qv[c] + B4[c0+c];
    Qp4[p*65 + c0 + c] = qv[c];
  }
  __syncthreads();
  const uchar* mi = (const uchar*)idxl + p*20;
  float Qs[32], Q2[32];
  #pragma unroll
  for (int c = 0; c < 32; ++c){ Qs[c]=0.f; Q2[c]=0.f; }
  for (int k = 0; k < KK; ++k){
    const int j = mi[k];
    #pragma unroll
    for (int c = 0; c < 32; ++c){
      const float q = Qp4[j*65 + c0 + c];
      Qs[c] += q; Q2[c] = fmaf(q, q, Q2[c]);
    }
  }
  #pragma unroll
  for (int c = 0; c < 32; ++c){
    float a = fmaf(20.f, pv[c], Qs[c]);
    float q = fmaf(20.f*pv[c], pv[c], fmaf(2.f*pv[c], Qs[c], Q2[c]));
    #pragma unroll
    for (int m = 32; m; m >>= 1){ a += __shfl_xor(a,m,64); q += __shfl_xor(q,m,64); }
    if ((t & 63) == 0){ atomicAdd(&ssum[c0+c], a); atomicAdd(&ssq[c0+c], q); }
  }
  __syncthreads();
  if (t < 64){
    unsafeAtomicAdd(&stat[t], (double)ssum[t]);
    unsafeAtomicAdd(&stat[64+t], (double)ssq[t]);
  }
}

// ---------------- EC2 output: mean_k relu(P'+Q') @ W5 + b5 -> x2 ----------------
__global__ __launch_bounds__(256) void ec2_m(const float* __restrict__ x1,
    const uchar* __restrict__ idx, const float* __restrict__ W4, const float* __restrict__ B4,
    const double* __restrict__ st4, const float* __restrict__ g4, const float* __restrict__ be4,
    const float* __restrict__ W5, const float* __restrict__ B5,
    float* __restrict__ x2){
  const int t = threadIdx.x, b = blockIdx.x;
  __shared__ float xm[128*65];    // X (stride 33) then mlds (stride 65) — lifetimes disjoint
  __shared__ float Qp4[128*65];
  __shared__ float sc4l[64], sh4l[64];
  __shared__ uint idxl[640];
  if (t < 64) bn_make(st4, 64, g4, be4, sc4l, sh4l, t);
  const float* xb = x1 + (size_t)b*4096;
  for (int i4 = t; i4 < 1024; i4 += 256){
    const float4 v = *(const float4*)&xb[i4*4];
    const int r = i4>>3, c = (i4&7)*4;
    xm[r*33+c]=v.x; xm[r*33+c+1]=v.y; xm[r*33+c+2]=v.z; xm[r*33+c+3]=v.w;
  }
  const uint* ig = (const uint*)(idx + (size_t)b*2560);
  for (int i = t; i < 640; i += 256) idxl[i] = ig[i];
  __syncthreads();
  const int p = t & 127;
  const int c0 = __builtin_amdgcn_readfirstlane((t>>7)*32);
  float xi[32];
  #pragma unroll
  for (int i = 0; i < 32; ++i) xi[i] = xm[p*33 + i];
  float t1[32], qv[32];
  #pragma unroll
  for (int c = 0; c < 32; ++c){ t1[c]=0.f; qv[c]=0.f; }
  #pragma unroll
  for (int i = 0; i < 32; ++i){
    const float v = xi[i];
    #pragma unroll
    for (int c = 0; c < 32; ++c){
      t1[c] = fmaf(v, W4[i*64 + c0 + c], t1[c]);        // uniform -> s_load
      qv[c] = fmaf(v, W4[(32+i)*64 + c0 + c], qv[c]);
    }
  }
  float pv[32];
  #pragma unroll
  for (int c = 0; c < 32; ++c){
    const float sc = sc4l[c0+c];
    pv[c] = fmaf(t1[c] - qv[c] + B4[c0+c], sc, sh4l[c0+c]);
    Qp4[p*65 + c0 + c] = qv[c]*sc;
  }
  __syncthreads();
  float macc[32];
  #pragma unroll
  for (int c = 0; c < 32; ++c) macc[c] = 0.f;
  const uchar* mi = (const uchar*)idxl + p*20;
  for (int k = 0; k < KK; ++k){
    const int j = mi[k];
    #pragma unroll
    for (int c = 0; c < 32; ++c)
      macc[c] += fmaxf(pv[c] + Qp4[j*65 + c0 + c], 0.f);
  }
  #pragma unroll
  for (int c = 0; c < 32; ++c) xm[p*65 + c0 + c] = macc[c] * INVK;   // mlds
  __syncthreads();
  // W5 phase: thread -> (point, 32-col group); W5 via uniform s_load
  const int pt = t & 127;
  const int og = __builtin_amdgcn_readfirstlane((t>>7)*32);
  float o[32];
  #pragma unroll
  for (int c = 0; c < 32; ++c) o[c] = B5[og + c];
  #pragma unroll
  for (int i = 0; i < 64; ++i){
    const float v = xm[pt*65 + i];
    #pragma unroll
    for (int c = 0; c < 32; ++c) o[c] = fmaf(v, W5[i*64 + og + c], o[c]);
  }
  float* ox = x2 + ((size_t)b*128 + pt)*64 + og;
  #pragma unroll
  for (int c4 = 0; c4 < 8; ++c4)
    *(float4*)&ox[c4*4] = make_float4(o[c4*4], o[c4*4+1], o[c4*4+2], o[c4*4+3]);
}

// ---------------- global max over N + head MLP ----------------
__global__ __launch_bounds__(128) void head_kernel(const float* __restrict__ x2,
    const float* __restrict__ w1, const float* __restrict__ b1,
    const float* __restrict__ w2, const float* __restrict__ b2,
    const float* __restrict__ w3, const float* __restrict__ b3,
    float* __restrict__ out){
  const int b = blockIdx.x, t = threadIdx.x;
  __shared__ float gmax[64];
  __shared__ float h1s[128];
  __shared__ float part[2];
  if (t < 64){
    const float* xb = x2 + (size_t)b * 128 * 64 + t;
    float m = -3.0e38f;
    for (int n = 0; n < 128; ++n) m = fmaxf(m, xb[n*64]);
    gmax[t] = m;
  }
  __syncthreads();
  float a = b1[t];
  #pragma unroll
  for (int i = 0; i < 64; ++i) a = fmaf(gmax[i], w1[i*128 + t], a);
  h1s[t] = fmaxf(a, 0.f);
  __syncthreads();
  float h2 = b2[t];
  #pragma unroll
  for (int i = 0; i < 128; ++i) h2 = fmaf(h1s[i], w2[i*128 + t], h2);
  h2 = fmaxf(h2, 0.f);
  float pr = h2 * w3[t];
  #pragma unroll
  for (int m = 32; m; m >>= 1) pr += __shfl_xor(pr, m, 64);
  if ((t & 63) == 0) part[t >> 6] = pr;
  __syncthreads();
  if (t == 0) out[b] = part[0] + part[1] + b3[0];
}

extern "C" void kernel_launch(void* const* d_in, const int* in_sizes, int n_in,
                              void* d_out, int out_size, void* d_ws, size_t ws_size,
                              hipStream_t stream) {
  const float* points = (const float*)d_in[0];
  const float* feat   = (const float*)d_in[1];
  const float* c1_w1  = (const float*)d_in[2];
  const float* c1_b1  = (const float*)d_in[3];
  const float* c1_g1  = (const float*)d_in[4];
  const float* c1_be1 = (const float*)d_in[5];
  const float* c1_w2  = (const float*)d_in[6];
  const float* c1_b2  = (const float*)d_in[7];
  const float* c1_g2  = (const float*)d_in[8];
  const float* c1_be2 = (const float*)d_in[9];
  const float* c1_w3  = (const float*)d_in[10];
  const float* c1_b3  = (const float*)d_in[11];
  const float* c2_w1  = (const float*)d_in[12];
  const float* c2_b1  = (const float*)d_in[13];
  const float* c2_g1  = (const float*)d_in[14];
  const float* c2_be1 = (const float*)d_in[15];
  const float* c2_w2  = (const float*)d_in[16];
  const float* c2_b2  = (const float*)d_in[17];
  const float* m_w1   = (const float*)d_in[18];
  const float* m_b1   = (const float*)d_in[19];
  const float* m_w2   = (const float*)d_in[20];
  const float* m_b2   = (const float*)d_in[21];
  const float* m_w3   = (const float*)d_in[22];
  const float* m_b3   = (const float*)d_in[23];
  float* out = (float*)d_out;

  char* ws = (char*)d_ws;
  const size_t NEDGE = (size_t)512 * 128 * KK;
  uchar*  idx1 = (uchar*)ws;
  uchar*  idx2 = (uchar*)(ws + NEDGE);
  float*  x1   = (float*)(ws + 2*NEDGE);                       // 8.39 MB
  float*  x2   = (float*)(ws + 2*NEDGE + (size_t)65536*32*4);  // 16.8 MB
  double* stats = (double*)(ws + 2*NEDGE + (size_t)65536*96*4);
  double* st1 = stats;         // [sum32 | sq32]  (h1)
  double* st2 = stats + 64;    // [sum32 | sq32]  (h2)
  double* st4 = stats + 128;   // [sum64 | sq64]  (h4)

  hipMemsetAsync(stats, 0, 256*sizeof(double), stream);

  knn1_kernel<<<512, 256, 0, stream>>>(points, idx1);
  pqs1      <<<512, 256, 0, stream>>>(feat, idx1, c1_w1, c1_b1, st1);
  ec1_s2    <<<512, 256, 0, stream>>>(feat, idx1, c1_w1, c1_b1, st1, c1_g1, c1_be1,
                                      c1_w2, c1_b2, st2);
  ec1_m     <<<512, 256, 0, stream>>>(feat, idx1, c1_w1, c1_b1, st1, c1_g1, c1_be1,
                                      c1_w2, c1_b2, st2, c1_g2, c1_be2, c1_w3, c1_b3, x1);
  knn2_kernel<<<512, 256, 0, stream>>>(x1, idx2);
  pqs4      <<<512, 256, 0, stream>>>(x1, idx2, c2_w1, c2_b1, st4);
  ec2_m     <<<512, 256, 0, stream>>>(x1, idx2, c2_w1, c2_b1, st4, c2_g1, c2_be1,
                                      c2_w2, c2_b2, x2);
  head_kernel<<<512, 128, 0, stream>>>(x2, m_w1, m_b1, m_w2, m_b2, m_w3, m_b3, out);
}